// Round 9
// baseline (167.439 us; speedup 1.0000x reference)
//
#include <hip/hip_runtime.h>

#define NPOS 589824   // 64*96*96
#define LN_EPS 1e-5f

typedef _Float16 half8 __attribute__((ext_vector_type(8)));
typedef _Float16 half2_t __attribute__((ext_vector_type(2)));
typedef float f32x4 __attribute__((ext_vector_type(4)));
typedef float f32x2 __attribute__((ext_vector_type(2)));

static __device__ __forceinline__ half2_t pk16(float a, float b) {
    return __builtin_bit_cast(half2_t, __builtin_amdgcn_cvt_pkrtz(a, b));
}

#define KB_BLOCKS 1152   // 1152 * 512 positions == NPOS
#define YSTR 520         // f16 row stride for the 512-wide Y tile

// ws layout (bytes):
//   [0, 16K)                 G24 (576 floats used) ; M 64x22 ; beta
//   [16K, 16K+4.72M)         stats: (mu,rin) per position
//   [16K+4.72M, +2.65M)      partials 1152 x 576
// total ~7.4 MB.  (The 576 MiB harness poison dispatch = d_ws, so ws >> this.)

// ---- kA: stats-only cold pass. Rolling s/sq, nothing parked -> ~50 VGPR ->
// high occupancy; TLP hides cold-HBM latency. 4 positions/thread, f32x4.
__global__ __launch_bounds__(256) void csa_stats(
    const float* __restrict__ x, float* __restrict__ stats)
{
    const int g = blockIdx.x * 256 + threadIdx.x;        // 0 .. NPOS/4-1
    const f32x4* __restrict__ x4 = (const f32x4*)x;
    f32x4 s = {0.f,0.f,0.f,0.f}, sq = s;
    #pragma unroll
    for (int c = 0; c < 64; ++c) {
        f32x4 v = x4[(size_t)c * (NPOS/4) + g];
        s += v;
        sq += v * v;
    }
    const f32x4 mu = s * (1.f/64.f);
    const f32x4 var = sq * (1.f/64.f) - mu * mu;
    f32x4 o0, o1;
    o0[0] = mu[0]; o0[2] = mu[1]; o1[0] = mu[2]; o1[2] = mu[3];
    o0[1] = rsqrtf(fmaxf(var[0], 0.f) + LN_EPS);
    o0[3] = rsqrtf(fmaxf(var[1], 0.f) + LN_EPS);
    o1[1] = rsqrtf(fmaxf(var[2], 0.f) + LN_EPS);
    o1[3] = rsqrtf(fmaxf(var[3], 0.f) + LN_EPS);
    f32x4* st4 = (f32x4*)stats;
    st4[2*g]     = o0;
    st4[2*g + 1] = o1;
}

// ---- kB: Gram pass. mu/rin precomputed -> no parking, 43 independent f32x2
// loads (ch 0..42 only = 101 MB, L3-warm), fused LN -> LDS, one barrier,
// round-8-verified MFMA + reduce.
// Y rows: 0..42 = y channels, 43 = ones, 44 = zeros.
// A row r: r<22->Y[r], r==22->Y[43], else Y[44].
// B row r (=ch 21+r): r<=21->Y[21+r], r==22->Y[43] (ch43=ones), else Y[44].
__global__ __launch_bounds__(256, 3) void csa_gram(
    const float* __restrict__ x, const float* __restrict__ lng,
    const float* __restrict__ lnb, const float* __restrict__ stats,
    float* __restrict__ partials)
{
    __shared__ __align__(16) _Float16 Y[45][YSTR];   // 46.8 KB -> 3 blocks/CU
    const int tid = threadIdx.x;
    const int lane = tid & 63;
    const int wv = tid >> 6;

    for (int i = tid; i < YSTR; i += 256) {
        Y[43][i] = (_Float16)1.0f;
        Y[44][i] = (_Float16)0.0f;
    }

    const int t = blockIdx.x * 256 + tid;            // owns positions 2t, 2t+1
    const f32x4 st = ((const f32x4*)stats)[t];       // mu0,rin0,mu1,rin1
    const float mu0 = st[0], rin0 = st[1], mu1 = st[2], rin1 = st[3];
    const int n0 = t * 2;
    #pragma unroll
    for (int c = 0; c < 43; ++c) {                   // all 43 loads independent
        f32x2 v = *(const f32x2*)(x + (size_t)c * NPOS + n0);
        const float g = lng[c], b = lnb[c];
        const float y0 = fmaf((v[0] - mu0) * rin0, g, b);
        const float y1 = fmaf((v[1] - mu1) * rin1, g, b);
        *(half2_t*)&Y[c][tid * 2] = pk16(y0, y1);
    }
    __syncthreads();

    f32x4 acc00 = {0.f,0.f,0.f,0.f}, acc01 = acc00, acc10 = acc00, acc11 = acc00;
    const int row = lane & 15;
    const int sub = (lane >> 4) & 3;
    const int kbase = wv * 128 + sub * 8;            // wave's 128-wide K slice
    const int r16 = row + 16;
    const int ra1 = (r16 < 22) ? r16 : ((r16 == 22) ? 43 : 44);
    const int rb1 = (r16 < 22) ? (r16 + 21) : ((r16 == 22) ? 43 : 44);
    #pragma unroll
    for (int s2 = 0; s2 < 4; ++s2) {
        const int kk = kbase + s2 * 32;
        half8 a0 = *(const half8*)&Y[row][kk];
        half8 a1 = *(const half8*)&Y[ra1][kk];
        half8 b0 = *(const half8*)&Y[row + 21][kk];
        half8 b1 = *(const half8*)&Y[rb1][kk];
        acc00 = __builtin_amdgcn_mfma_f32_16x16x32_f16(a0, b0, acc00, 0, 0, 0);
        acc01 = __builtin_amdgcn_mfma_f32_16x16x32_f16(a0, b1, acc01, 0, 0, 0);
        acc10 = __builtin_amdgcn_mfma_f32_16x16x32_f16(a1, b0, acc10, 0, 0, 0);
        acc11 = __builtin_amdgcn_mfma_f32_16x16x32_f16(a1, b1, acc11, 0, 0, 0);
    }
    __syncthreads();

    float* G32 = (float*)&Y[0][0];
    for (int e = tid; e < 1024; e += 256) G32[e] = 0.f;
    __syncthreads();
    const int r0 = (lane >> 4) * 4, c0 = lane & 15;
    #pragma unroll
    for (int r = 0; r < 4; ++r) {
        atomicAdd(&G32[(r0 + r) * 32 + c0],            acc00[r]);
        atomicAdd(&G32[(r0 + r) * 32 + 16 + c0],       acc01[r]);
        atomicAdd(&G32[(16 + r0 + r) * 32 + c0],       acc10[r]);
        atomicAdd(&G32[(16 + r0 + r) * 32 + 16 + c0],  acc11[r]);
    }
    __syncthreads();
    for (int e = tid; e < 576; e += 256) {           // used 24x24 corner only
        const int r = e / 24, c = e % 24;
        partials[(size_t)blockIdx.x * 576 + e] = G32[r * 32 + c];
    }
}

// 576 outputs; 16 lanes per output, shuffle-reduced.
__global__ __launch_bounds__(256) void csa_k2(const float* __restrict__ partials,
                                              float* __restrict__ gfin)
{
    const int tid = threadIdx.x;
    const int e = blockIdx.x * 16 + (tid >> 4);      // 36 blocks * 16 = 576
    const int g = tid & 15;
    float s = 0.f;
    for (int b = g; b < KB_BLOCKS; b += 16)
        s += partials[(size_t)b * 576 + e];
    s += __shfl_down(s, 8, 16);
    s += __shfl_down(s, 4, 16);
    s += __shfl_down(s, 2, 16);
    s += __shfl_down(s, 1, 16);
    if (g == 0) gfin[e] = s;
}

__global__ void csa_k3(const float* __restrict__ G, const float* __restrict__ cw,
                       const float* __restrict__ cb, float* __restrict__ M,
                       float* __restrict__ betaO)
{
    const int c = threadIdx.x;       // 64 threads, one output row each
    __shared__ float lg[64][65];
    const float wq = cw[c], bq = cb[c];
    const int a = c / 3;
    const float Sa = G[a * 24 + 22];
    float mx = -1e30f;
    #pragma unroll
    for (int k = 0; k < 64; ++k) {
        const float wk = cw[64 + k], bk = cb[64 + k];
        const int b = (64 + k) / 3 - 21;
        const float Gab = G[a * 24 + b];
        const float Sb  = G[22 * 24 + b];
        float lo = 0.125f * (wq * wk * Gab + wq * bk * Sa + bq * wk * Sb
                             + bq * bk * (float)NPOS);
        lg[c][k] = lo;
        mx = fmaxf(mx, lo);
    }
    float sum = 0.f;
    #pragma unroll
    for (int k = 0; k < 64; ++k) {
        float e = expf(lg[c][k] - mx);
        lg[c][k] = e; sum += e;
    }
    const float inv = 1.f / sum;
    float Ml[22];
    #pragma unroll
    for (int m = 0; m < 22; ++m) Ml[m] = 0.f;
    float bacc = 0.f;
    #pragma unroll
    for (int k = 0; k < 64; ++k) {
        const float attn = lg[c][k] * inv;
        const int mm = (128 + k) / 3 - 42;
        Ml[mm] = fmaf(attn, cw[128 + k], Ml[mm]);
        bacc   = fmaf(attn, cb[128 + k], bacc);
    }
    #pragma unroll
    for (int m = 0; m < 22; ++m) M[c * 22 + m] = Ml[m];
    betaO[c] = bacc;
}

// Output kernel: 2 positions/thread, f32x2 loads, f32x2 nontemporal stores.
__global__ __launch_bounds__(256, 2) void csa_k4(
    const float* __restrict__ x, const float* __restrict__ lng,
    const float* __restrict__ lnb, const float* __restrict__ M,
    const float* __restrict__ betaO, float* __restrict__ out)
{
    const int n0 = (blockIdx.x * 256 + threadIdx.x) * 2;
    f32x2 xv[64];
    f32x2 s = {0.f, 0.f}, sq = s;
    #pragma unroll
    for (int c = 0; c < 64; ++c) {
        f32x2 v = *(const f32x2*)(x + (size_t)c * NPOS + n0);
        xv[c] = v; s += v; sq += v * v;
    }
    const f32x2 mu = s * (1.f/64.f);
    const f32x2 var = sq * (1.f/64.f) - mu * mu;
    const float rin0 = rsqrtf(fmaxf(var[0], 0.f) + LN_EPS);
    const float rin1 = rsqrtf(fmaxf(var[1], 0.f) + LN_EPS);
    f32x2 y[22];
    #pragma unroll
    for (int m = 0; m < 22; ++m) {
        const float g = lng[42 + m], b = lnb[42 + m];
        y[m][0] = fmaf((xv[42 + m][0] - mu[0]) * rin0, g, b);
        y[m][1] = fmaf((xv[42 + m][1] - mu[1]) * rin1, g, b);
    }
    #pragma unroll
    for (int c = 0; c < 64; ++c) {
        const float bb = betaO[c];
        f32x2 a = {bb, bb};
        #pragma unroll
        for (int m = 0; m < 22; ++m) {
            const float w = M[c * 22 + m];       // uniform -> scalar
            a[0] = fmaf(w, y[m][0], a[0]);
            a[1] = fmaf(w, y[m][1], a[1]);
        }
        f32x2 o = xv[c] + a;
        __builtin_nontemporal_store(o, (f32x2*)(out + (size_t)c * NPOS + n0));
    }
}

extern "C" void kernel_launch(void* const* d_in, const int* in_sizes, int n_in,
                              void* d_out, int out_size, void* d_ws, size_t ws_size,
                              hipStream_t stream) {
    const float* x   = (const float*)d_in[0];
    const float* lng = (const float*)d_in[1];
    const float* lnb = (const float*)d_in[2];
    const float* cw  = (const float*)d_in[3];
    const float* cb  = (const float*)d_in[4];
    float* out = (float*)d_out;

    float* wsf   = (float*)d_ws;
    float* Gf    = wsf;                               // 576 used
    float* Mf    = wsf + 1024;                        // 64*22
    float* Bf    = wsf + 1024 + 64 * 22;              // 64
    float* stats = (float*)((char*)d_ws + 16384);     // NPOS*2 floats = 4.72 MB
    float* Pf    = (float*)((char*)d_ws + 16384 + (size_t)NPOS * 8); // 2.65 MB

    hipLaunchKernelGGL(csa_stats, dim3(NPOS / 1024), dim3(256), 0, stream,
                       x, stats);
    hipLaunchKernelGGL(csa_gram, dim3(KB_BLOCKS), dim3(256), 0, stream,
                       x, lng, lnb, stats, Pf);
    hipLaunchKernelGGL(csa_k2, dim3(36), dim3(256), 0, stream, Pf, Gf);
    hipLaunchKernelGGL(csa_k3, dim3(1), dim3(64), 0, stream, Gf, cw, cb, Mf, Bf);
    hipLaunchKernelGGL(csa_k4, dim3(NPOS / 512), dim3(256), 0, stream,
                       x, lng, lnb, Mf, Bf, out);
}

// Round 11
// 151.297 us; speedup vs baseline: 1.1067x; 1.1067x over previous
//
#include <hip/hip_runtime.h>

#define NPOS 589824   // 64*96*96
#define LN_EPS 1e-5f

typedef _Float16 half8 __attribute__((ext_vector_type(8)));
typedef float f32x4 __attribute__((ext_vector_type(4)));
typedef float f32x2 __attribute__((ext_vector_type(2)));

#define K1_BLOCKS 1152
#define TILE 128      // positions per chunk
#define CPB 4         // chunks per block: 1152*4*128 == NPOS
#define YSTR 136      // f16 row stride (128 + 8 pad)

// ws layout (bytes): [0,16K) G24/M/beta ; [16K, 16K+2.65M) partials.

// LN + Gram, channel-split for occupancy: thread t<128 loads ch 0..31 of
// position p=tid&127; t>=128 loads ch 32..63. xv[32] (~80 VGPR) instead of
// xv[64] (~130) -> launch_bounds(256,4) -> ~16 waves/CU to hide cold-HBM
// latency. Stats joined via LDS. MFMA mapping as verified (R7/R8): wave wv
// covers K slice [wv*32, wv*32+32), sub=(lane>>4) picks 8 cols.
// Y rows: 0..42 = y channels, 43 = ones, 44 = zeros.
__global__ __launch_bounds__(256, 4) void csa_k1(
    const float* __restrict__ x, const float* __restrict__ lng,
    const float* __restrict__ lnb, float* __restrict__ partials)
{
    __shared__ __align__(16) _Float16 Y[45][YSTR];   // 12240 B
    __shared__ float SS[256], QQ[256];               // 2048 B
    const int tid = threadIdx.x;
    const int lane = tid & 63;
    const int wv = tid >> 6;
    const int p127 = tid & 127;                      // position within tile
    const int c0 = (tid >> 7) * 32;                  // 0 or 32 (wave-uniform)

    for (int i = tid; i < YSTR; i += 256) {
        Y[43][i] = (_Float16)1.0f;
        Y[44][i] = (_Float16)0.0f;
    }

    f32x4 acc00 = {0.f,0.f,0.f,0.f}, acc01 = acc00, acc10 = acc00, acc11 = acc00;
    const int row = lane & 15;
    const int sub = (lane >> 4) & 3;
    const int kk = wv * 32 + sub * 8;                // this wave's K cols
    const int r16 = row + 16;
    const int ra1 = (r16 < 22) ? r16 : ((r16 == 22) ? 43 : 44);
    const int rb1 = (r16 < 22) ? (r16 + 21) : ((r16 == 22) ? 43 : 44);
    const int pos0 = blockIdx.x * (CPB * TILE);

    for (int ck = 0; ck < CPB; ++ck) {
        const int n = pos0 + ck * TILE + p127;
        float xv[32];
        #pragma unroll
        for (int i = 0; i < 32; ++i)                 // 32 independent loads
            xv[i] = x[(size_t)(c0 + i) * NPOS + n];
        float s = 0.f, sq = 0.f;
        #pragma unroll
        for (int i = 0; i < 32; ++i) { s += xv[i]; sq = fmaf(xv[i], xv[i], sq); }
        SS[tid] = s; QQ[tid] = sq;
        __syncthreads();
        const float st = SS[p127] + SS[p127 + 128];
        const float qt = QQ[p127] + QQ[p127 + 128];
        const float mu  = st * (1.f/64.f);
        const float var = fmaf(-mu, mu, qt * (1.f/64.f));
        const float rin = rsqrtf(fmaxf(var, 0.f) + LN_EPS);
        if (c0 == 0) {                               // wave-uniform branch
            #pragma unroll
            for (int i = 0; i < 32; ++i)
                Y[i][p127] = (_Float16)fmaf((xv[i] - mu) * rin, lng[i], lnb[i]);
        } else {
            #pragma unroll
            for (int i = 0; i < 11; ++i)             // ch 32..42 only
                Y[32 + i][p127] =
                    (_Float16)fmaf((xv[i] - mu) * rin, lng[32 + i], lnb[32 + i]);
        }
        __syncthreads();
        half8 a0 = *(const half8*)&Y[row][kk];
        half8 a1 = *(const half8*)&Y[ra1][kk];
        half8 b0 = *(const half8*)&Y[row + 21][kk];
        half8 b1 = *(const half8*)&Y[rb1][kk];
        acc00 = __builtin_amdgcn_mfma_f32_16x16x32_f16(a0, b0, acc00, 0, 0, 0);
        acc01 = __builtin_amdgcn_mfma_f32_16x16x32_f16(a0, b1, acc01, 0, 0, 0);
        acc10 = __builtin_amdgcn_mfma_f32_16x16x32_f16(a1, b0, acc10, 0, 0, 0);
        acc11 = __builtin_amdgcn_mfma_f32_16x16x32_f16(a1, b1, acc11, 0, 0, 0);
        __syncthreads();
    }

    // block-level reduce of the 4 waves' fragments (reuse Y as float scratch)
    float* G32 = (float*)&Y[0][0];
    for (int e = tid; e < 1024; e += 256) G32[e] = 0.f;
    __syncthreads();
    const int r0 = (lane >> 4) * 4, cc = lane & 15;
    #pragma unroll
    for (int r = 0; r < 4; ++r) {
        atomicAdd(&G32[(r0 + r) * 32 + cc],            acc00[r]);
        atomicAdd(&G32[(r0 + r) * 32 + 16 + cc],       acc01[r]);
        atomicAdd(&G32[(16 + r0 + r) * 32 + cc],       acc10[r]);
        atomicAdd(&G32[(16 + r0 + r) * 32 + 16 + cc],  acc11[r]);
    }
    __syncthreads();
    for (int e = tid; e < 576; e += 256) {           // used 24x24 corner only
        const int r = e / 24, c = e % 24;
        partials[(size_t)blockIdx.x * 576 + e] = G32[r * 32 + c];
    }
}

// 576 outputs; 16 lanes per output, shuffle-reduced.
__global__ __launch_bounds__(256) void csa_k2(const float* __restrict__ partials,
                                              float* __restrict__ gfin)
{
    const int tid = threadIdx.x;
    const int e = blockIdx.x * 16 + (tid >> 4);      // 36 blocks * 16 = 576
    const int g = tid & 15;
    float s = 0.f;
    for (int b = g; b < K1_BLOCKS; b += 16)
        s += partials[(size_t)b * 576 + e];
    s += __shfl_down(s, 8, 16);
    s += __shfl_down(s, 4, 16);
    s += __shfl_down(s, 2, 16);
    s += __shfl_down(s, 1, 16);
    if (g == 0) gfin[e] = s;
}

__global__ void csa_k3(const float* __restrict__ G, const float* __restrict__ cw,
                       const float* __restrict__ cb, float* __restrict__ M,
                       float* __restrict__ betaO)
{
    const int c = threadIdx.x;       // 64 threads, one output row each
    __shared__ float lg[64][65];
    const float wq = cw[c], bq = cb[c];
    const int a = c / 3;
    const float Sa = G[a * 24 + 22];
    float mx = -1e30f;
    #pragma unroll
    for (int k = 0; k < 64; ++k) {
        const float wk = cw[64 + k], bk = cb[64 + k];
        const int b = (64 + k) / 3 - 21;
        const float Gab = G[a * 24 + b];
        const float Sb  = G[22 * 24 + b];
        float lo = 0.125f * (wq * wk * Gab + wq * bk * Sa + bq * wk * Sb
                             + bq * bk * (float)NPOS);
        lg[c][k] = lo;
        mx = fmaxf(mx, lo);
    }
    float sum = 0.f;
    #pragma unroll
    for (int k = 0; k < 64; ++k) {
        float e = expf(lg[c][k] - mx);
        lg[c][k] = e; sum += e;
    }
    const float inv = 1.f / sum;
    float Ml[22];
    #pragma unroll
    for (int m = 0; m < 22; ++m) Ml[m] = 0.f;
    float bacc = 0.f;
    #pragma unroll
    for (int k = 0; k < 64; ++k) {
        const float attn = lg[c][k] * inv;
        const int mm = (128 + k) / 3 - 42;
        Ml[mm] = fmaf(attn, cw[128 + k], Ml[mm]);
        bacc   = fmaf(attn, cb[128 + k], bacc);
    }
    #pragma unroll
    for (int m = 0; m < 22; ++m) M[c * 22 + m] = Ml[m];
    betaO[c] = bacc;
}

// Output kernel: 2 positions/thread, f32x2 loads, f32x2 nontemporal stores.
__global__ __launch_bounds__(256, 2) void csa_k4(
    const float* __restrict__ x, const float* __restrict__ lng,
    const float* __restrict__ lnb, const float* __restrict__ M,
    const float* __restrict__ betaO, float* __restrict__ out)
{
    const int n0 = (blockIdx.x * 256 + threadIdx.x) * 2;
    f32x2 xv[64];
    f32x2 s = {0.f, 0.f}, sq = s;
    #pragma unroll
    for (int c = 0; c < 64; ++c) {
        f32x2 v = *(const f32x2*)(x + (size_t)c * NPOS + n0);
        xv[c] = v; s += v; sq += v * v;
    }
    const f32x2 mu = s * (1.f/64.f);
    const f32x2 var = sq * (1.f/64.f) - mu * mu;
    const float rin0 = rsqrtf(fmaxf(var[0], 0.f) + LN_EPS);
    const float rin1 = rsqrtf(fmaxf(var[1], 0.f) + LN_EPS);
    f32x2 y[22];
    #pragma unroll
    for (int m = 0; m < 22; ++m) {
        const float g = lng[42 + m], b = lnb[42 + m];
        y[m][0] = fmaf((xv[42 + m][0] - mu[0]) * rin0, g, b);
        y[m][1] = fmaf((xv[42 + m][1] - mu[1]) * rin1, g, b);
    }
    #pragma unroll
    for (int c = 0; c < 64; ++c) {
        const float bb = betaO[c];
        f32x2 a = {bb, bb};
        #pragma unroll
        for (int m = 0; m < 22; ++m) {
            const float w = M[c * 22 + m];       // uniform -> scalar
            a[0] = fmaf(w, y[m][0], a[0]);
            a[1] = fmaf(w, y[m][1], a[1]);
        }
        f32x2 o = xv[c] + a;
        __builtin_nontemporal_store(o, (f32x2*)(out + (size_t)c * NPOS + n0));
    }
}

extern "C" void kernel_launch(void* const* d_in, const int* in_sizes, int n_in,
                              void* d_out, int out_size, void* d_ws, size_t ws_size,
                              hipStream_t stream) {
    const float* x   = (const float*)d_in[0];
    const float* lng = (const float*)d_in[1];
    const float* lnb = (const float*)d_in[2];
    const float* cw  = (const float*)d_in[3];
    const float* cb  = (const float*)d_in[4];
    float* out = (float*)d_out;

    float* wsf = (float*)d_ws;
    float* Gf  = wsf;                                 // 576 used
    float* Mf  = wsf + 1024;                          // 64*22
    float* Bf  = wsf + 1024 + 64 * 22;                // 64
    float* Pf  = (float*)((char*)d_ws + 16384);       // 1152*576 floats

    hipLaunchKernelGGL(csa_k1, dim3(K1_BLOCKS), dim3(256), 0, stream,
                       x, lng, lnb, Pf);
    hipLaunchKernelGGL(csa_k2, dim3(36), dim3(256), 0, stream, Pf, Gf);
    hipLaunchKernelGGL(csa_k3, dim3(1), dim3(64), 0, stream, Gf, cw, cb, Mf, Bf);
    hipLaunchKernelGGL(csa_k4, dim3(NPOS / 512), dim3(256), 0, stream,
                       x, lng, lnb, Mf, Bf, out);
}